// Round 2
// baseline (292.832 us; speedup 1.0000x reference)
//
#include <hip/hip_runtime.h>
#include <hip/hip_bf16.h>
#include <stdint.h>

#define D_MODEL 768
#define N_HEADS 12
#define D_HEAD  64
#define BATCH   2
#define SEQ     2048
#define M_TOTAL (BATCH*SEQ)   /* 4096 */
#define N_QKV   (3*D_MODEL)   /* 2304 */

typedef float  floatx4 __attribute__((ext_vector_type(4)));
typedef short  shortx8 __attribute__((ext_vector_type(8)));

static __device__ __forceinline__ unsigned short f2bf(float f) {
  union { float f; uint32_t u; } v; v.f = f;
  uint32_t u = v.u;
  return (unsigned short)((u + 0x7fffu + ((u >> 16) & 1u)) >> 16);
}

static __device__ __forceinline__ void gload_lds16(const void* g, void* l) {
  auto gp = reinterpret_cast<const uint32_t __attribute__((address_space(1)))*>(
      reinterpret_cast<uintptr_t>(g));
  auto lp = reinterpret_cast<uint32_t __attribute__((address_space(3)))*>(
      reinterpret_cast<uintptr_t>(l));
  __builtin_amdgcn_global_load_lds(gp, lp, 16, 0, 0);
}

/* ---------------- convert fp32 -> bf16 (x, W_qkv, W_o) ---------------- */
__global__ void convert_bf16_kernel(const float* __restrict__ x,
                                    const float* __restrict__ wqkv,
                                    const float* __restrict__ wo,
                                    unsigned short* __restrict__ xb,
                                    unsigned short* __restrict__ wqkvb,
                                    unsigned short* __restrict__ wob) {
  const int NX = M_TOTAL * D_MODEL / 4;   // 786432
  const int NW = N_QKV * D_MODEL / 4;     // 442368
  const int NO = D_MODEL * D_MODEL / 4;   // 147456
  const int total = NX + NW + NO;
  for (int i = blockIdx.x * blockDim.x + threadIdx.x; i < total;
       i += gridDim.x * blockDim.x) {
    const float4* src; unsigned short* dst; int j;
    if (i < NX)            { src = (const float4*)x;    dst = xb;    j = i; }
    else if (i < NX + NW)  { src = (const float4*)wqkv; dst = wqkvb; j = i - NX; }
    else                   { src = (const float4*)wo;   dst = wob;   j = i - NX - NW; }
    float4 v = src[j];
    ushort4 o;
    o.x = f2bf(v.x); o.y = f2bf(v.y); o.z = f2bf(v.z); o.w = f2bf(v.w);
    *(ushort4*)(dst + (size_t)j * 4) = o;
  }
}

/* ---------------- QKV projection GEMM: [4096,768] @ [2304,768]^T ----------------
   Writes Q (scaled by 0.125), K as [b,h,s,64] bf16; V transposed as [b,h,64,s]. */
__launch_bounds__(256, 2)
__global__ void qkv_gemm_kernel(const unsigned short* __restrict__ Xb,
                                const unsigned short* __restrict__ Wb,
                                const float* __restrict__ bias,
                                unsigned short* __restrict__ Qb,
                                unsigned short* __restrict__ Kb,
                                unsigned short* __restrict__ Vt) {
  __shared__ unsigned short Asub[128 * 32];
  __shared__ unsigned short Bsub[128 * 32];
  const int tid  = threadIdx.x;
  const int wave = tid >> 6;
  const int lane = tid & 63;
  const int m0 = blockIdx.y * 128;
  const int n0 = blockIdx.x * 128;
  const int wm = (wave >> 1) * 64;
  const int wn = (wave & 1) * 64;
  const int srow = lane >> 2;          // 0..15 within chunk
  const int scol = (lane & 3) * 8;     // k element offset
  const int col  = lane & 15;
  const int grp  = lane >> 4;
  floatx4 acc[4][4] = {};
  for (int kt = 0; kt < D_MODEL; kt += 32) {
    #pragma unroll
    for (int i = 0; i < 2; ++i) {
      int c = wave * 2 + i;
      int row = c * 16 + srow;
      gload_lds16(Xb + (size_t)(m0 + row) * D_MODEL + kt + scol, &Asub[c * 512]);
      gload_lds16(Wb + (size_t)(n0 + row) * D_MODEL + kt + scol, &Bsub[c * 512]);
    }
    __syncthreads();
    shortx8 af[4], bf[4];
    #pragma unroll
    for (int t = 0; t < 4; ++t) {
      af[t] = *(const shortx8*)&Asub[(wm + t * 16 + col) * 32 + grp * 8];
      bf[t] = *(const shortx8*)&Bsub[(wn + t * 16 + col) * 32 + grp * 8];
    }
    #pragma unroll
    for (int i = 0; i < 4; ++i)
      #pragma unroll
      for (int j = 0; j < 4; ++j)
        acc[i][j] = __builtin_amdgcn_mfma_f32_16x16x32_bf16(af[i], bf[j], acc[i][j], 0, 0, 0);
    __syncthreads();
  }
  /* epilogue: route to Q / K / Vt */
  #pragma unroll
  for (int i = 0; i < 4; ++i) {
    int mbase = m0 + wm + i * 16 + grp * 4;
    int b = mbase >> 11;
    int s = mbase & 2047;
    #pragma unroll
    for (int j = 0; j < 4; ++j) {
      int n   = n0 + wn + j * 16 + col;
      int sel = n / D_MODEL;
      int c   = n % D_MODEL;
      int h   = c >> 6, d = c & 63;
      int bh  = b * N_HEADS + h;
      float bv = bias[n];
      if (sel == 0) {
        #pragma unroll
        for (int r = 0; r < 4; ++r)
          Qb[((size_t)bh * SEQ + s + r) * D_HEAD + d] = f2bf((acc[i][j][r] + bv) * 0.125f);
      } else if (sel == 1) {
        #pragma unroll
        for (int r = 0; r < 4; ++r)
          Kb[((size_t)bh * SEQ + s + r) * D_HEAD + d] = f2bf(acc[i][j][r] + bv);
      } else {
        ushort4 o;
        o.x = f2bf(acc[i][j][0] + bv);
        o.y = f2bf(acc[i][j][1] + bv);
        o.z = f2bf(acc[i][j][2] + bv);
        o.w = f2bf(acc[i][j][3] + bv);
        *(ushort4*)&Vt[((size_t)bh * D_HEAD + d) * SEQ + s] = o;
      }
    }
  }
}

/* ---------------- causal flash attention ----------------
   grid (32 q-tiles, 24 b*h); 4 waves/block, each wave = 16 q rows, KV tile 64. */
__launch_bounds__(256, 2)
__global__ void attn_kernel(const unsigned short* __restrict__ Qb,
                            const unsigned short* __restrict__ Kb,
                            const unsigned short* __restrict__ Vt,
                            unsigned short* __restrict__ Zb) {
  __shared__ unsigned short P_lds[4][16 * 64];   // per-wave private, XOR-swizzled
  const int tid  = threadIdx.x;
  const int wave = tid >> 6;
  const int lane = tid & 63;
  const int qt = blockIdx.x;
  const int bh = blockIdx.y;
  const int col = lane & 15;
  const int grp = lane >> 4;
  const int q0  = qt * 64 + wave * 16;

  const unsigned short* Qrow = Qb + ((size_t)bh * SEQ + q0 + col) * D_HEAD;
  shortx8 qf0 = *(const shortx8*)(Qrow + grp * 8);
  shortx8 qf1 = *(const shortx8*)(Qrow + 32 + grp * 8);

  floatx4 acc[4] = {};
  float mrun[4], lrun[4];
  #pragma unroll
  for (int r = 0; r < 4; ++r) { mrun[r] = -1e30f; lrun[r] = 0.f; }

  unsigned short* pw = P_lds[wave];
  const int ktiles = qt + 1;
  for (int kt = 0; kt < ktiles; ++kt) {
    const int kv0 = kt * 64;
    /* S = Q K^T (pre-scaled Q) */
    floatx4 st[4];
    #pragma unroll
    for (int nt = 0; nt < 4; ++nt) {
      const unsigned short* Krow = Kb + ((size_t)bh * SEQ + kv0 + nt * 16 + col) * D_HEAD;
      shortx8 kf0 = *(const shortx8*)(Krow + grp * 8);
      shortx8 kf1 = *(const shortx8*)(Krow + 32 + grp * 8);
      floatx4 s = {};
      s = __builtin_amdgcn_mfma_f32_16x16x32_bf16(qf0, kf0, s, 0, 0, 0);
      s = __builtin_amdgcn_mfma_f32_16x16x32_bf16(qf1, kf1, s, 0, 0, 0);
      st[nt] = s;
    }
    /* causal mask + online softmax */
    #pragma unroll
    for (int r = 0; r < 4; ++r) {
      int q = q0 + grp * 4 + r;
      float tmax = -1e30f;
      #pragma unroll
      for (int nt = 0; nt < 4; ++nt) {
        int kv = kv0 + nt * 16 + col;
        float sv = (kv <= q) ? st[nt][r] : -1e30f;
        st[nt][r] = sv;
        tmax = fmaxf(tmax, sv);
      }
      tmax = fmaxf(tmax, __shfl_xor(tmax, 1));
      tmax = fmaxf(tmax, __shfl_xor(tmax, 2));
      tmax = fmaxf(tmax, __shfl_xor(tmax, 4));
      tmax = fmaxf(tmax, __shfl_xor(tmax, 8));
      float mnew  = fmaxf(mrun[r], tmax);
      float alpha = __expf(mrun[r] - mnew);
      mrun[r] = mnew;
      float rs = 0.f;
      #pragma unroll
      for (int nt = 0; nt < 4; ++nt) {
        float p = __expf(st[nt][r] - mnew);
        st[nt][r] = p;
        rs += p;
      }
      rs += __shfl_xor(rs, 1);
      rs += __shfl_xor(rs, 2);
      rs += __shfl_xor(rs, 4);
      rs += __shfl_xor(rs, 8);
      lrun[r] = lrun[r] * alpha + rs;
      #pragma unroll
      for (int dn = 0; dn < 4; ++dn) acc[dn][r] *= alpha;
    }
    /* P -> bf16 -> per-wave LDS (XOR swizzle: byte ^= (row&7)<<4) */
    #pragma unroll
    for (int nt = 0; nt < 4; ++nt) {
      #pragma unroll
      for (int r = 0; r < 4; ++r) {
        int row = grp * 4 + r;
        int cb  = (nt * 32 + col * 2) ^ ((row & 7) << 4);
        pw[row * 64 + (cb >> 1)] = f2bf(st[nt][r]);
      }
    }
    /* Z += P V  (Vt gives contiguous B-fragments) */
    #pragma unroll
    for (int ks = 0; ks < 2; ++ks) {
      int base = ((ks * 64 + grp * 16) ^ ((col & 7) << 4)) >> 1;
      shortx8 pf = *(const shortx8*)&pw[col * 64 + base];
      #pragma unroll
      for (int dn = 0; dn < 4; ++dn) {
        const unsigned short* Vrow =
            Vt + ((size_t)bh * D_HEAD + dn * 16 + col) * SEQ + kv0 + ks * 32 + grp * 8;
        shortx8 vf = *(const shortx8*)Vrow;
        acc[dn] = __builtin_amdgcn_mfma_f32_16x16x32_bf16(pf, vf, acc[dn], 0, 0, 0);
      }
    }
  }
  /* normalize and write Z [b, s, 768] bf16 */
  const int b = bh / N_HEADS, h = bh % N_HEADS;
  #pragma unroll
  for (int dn = 0; dn < 4; ++dn) {
    #pragma unroll
    for (int r = 0; r < 4; ++r) {
      int q = q0 + grp * 4 + r;
      float o = acc[dn][r] / lrun[r];
      Zb[((size_t)b * SEQ + q) * D_MODEL + h * 64 + dn * 16 + col] = f2bf(o);
    }
  }
}

/* ---------------- output projection: [4096,768] @ [768,768]^T + b_o -> fp32 ---- */
__launch_bounds__(256, 2)
__global__ void out_gemm_kernel(const unsigned short* __restrict__ Zb,
                                const unsigned short* __restrict__ Wob,
                                const float* __restrict__ bo,
                                float* __restrict__ Out) {
  __shared__ unsigned short Asub[128 * 32];
  __shared__ unsigned short Bsub[128 * 32];
  const int tid  = threadIdx.x;
  const int wave = tid >> 6;
  const int lane = tid & 63;
  const int m0 = blockIdx.y * 128;
  const int n0 = blockIdx.x * 128;
  const int wm = (wave >> 1) * 64;
  const int wn = (wave & 1) * 64;
  const int srow = lane >> 2;
  const int scol = (lane & 3) * 8;
  const int col  = lane & 15;
  const int grp  = lane >> 4;
  floatx4 acc[4][4] = {};
  for (int kt = 0; kt < D_MODEL; kt += 32) {
    #pragma unroll
    for (int i = 0; i < 2; ++i) {
      int c = wave * 2 + i;
      int row = c * 16 + srow;
      gload_lds16(Zb  + (size_t)(m0 + row) * D_MODEL + kt + scol, &Asub[c * 512]);
      gload_lds16(Wob + (size_t)(n0 + row) * D_MODEL + kt + scol, &Bsub[c * 512]);
    }
    __syncthreads();
    shortx8 af[4], bf[4];
    #pragma unroll
    for (int t = 0; t < 4; ++t) {
      af[t] = *(const shortx8*)&Asub[(wm + t * 16 + col) * 32 + grp * 8];
      bf[t] = *(const shortx8*)&Bsub[(wn + t * 16 + col) * 32 + grp * 8];
    }
    #pragma unroll
    for (int i = 0; i < 4; ++i)
      #pragma unroll
      for (int j = 0; j < 4; ++j)
        acc[i][j] = __builtin_amdgcn_mfma_f32_16x16x32_bf16(af[i], bf[j], acc[i][j], 0, 0, 0);
    __syncthreads();
  }
  #pragma unroll
  for (int i = 0; i < 4; ++i) {
    int mbase = m0 + wm + i * 16 + grp * 4;
    #pragma unroll
    for (int j = 0; j < 4; ++j) {
      int n = n0 + wn + j * 16 + col;
      float bv = bo[n];
      #pragma unroll
      for (int r = 0; r < 4; ++r)
        Out[(size_t)(mbase + r) * D_MODEL + n] = acc[i][j][r] + bv;
    }
  }
}

/* ---------------- launcher ---------------- */
extern "C" void kernel_launch(void* const* d_in, const int* in_sizes, int n_in,
                              void* d_out, int out_size, void* d_ws, size_t ws_size,
                              hipStream_t stream) {
  const float* x    = (const float*)d_in[0];
  const float* Wqkv = (const float*)d_in[1];
  const float* bqkv = (const float*)d_in[2];
  const float* Wo   = (const float*)d_in[3];
  const float* bo   = (const float*)d_in[4];
  float* out = (float*)d_out;

  unsigned short* ws = (unsigned short*)d_ws;
  const size_t SZ_X   = (size_t)M_TOTAL * D_MODEL;   // 3,145,728
  const size_t SZ_WQ  = (size_t)N_QKV * D_MODEL;     // 1,769,472
  const size_t SZ_WO  = (size_t)D_MODEL * D_MODEL;   //   589,824
  unsigned short* Xb    = ws;
  unsigned short* Wqkvb = Xb + SZ_X;
  unsigned short* Wob   = Wqkvb + SZ_WQ;
  unsigned short* Qb    = Wob + SZ_WO;
  unsigned short* Kb    = Qb + SZ_X;
  unsigned short* Vt    = Kb + SZ_X;
  unsigned short* Zb    = Vt + SZ_X;

  convert_bf16_kernel<<<dim3(1024), dim3(256), 0, stream>>>(x, Wqkv, Wo, Xb, Wqkvb, Wob);
  qkv_gemm_kernel<<<dim3(N_QKV / 128, M_TOTAL / 128), dim3(256), 0, stream>>>(
      Xb, Wqkvb, bqkv, Qb, Kb, Vt);
  attn_kernel<<<dim3(SEQ / 64, BATCH * N_HEADS), dim3(256), 0, stream>>>(Qb, Kb, Vt, Zb);
  out_gemm_kernel<<<dim3(D_MODEL / 128, M_TOTAL / 128), dim3(256), 0, stream>>>(
      Zb, Wob, bo, out);
}

// Round 3
// 233.871 us; speedup vs baseline: 1.2521x; 1.2521x over previous
//
#include <hip/hip_runtime.h>
#include <hip/hip_bf16.h>
#include <stdint.h>

#define D_MODEL 768
#define N_HEADS 12
#define D_HEAD  64
#define BATCH   2
#define SEQ     2048
#define M_TOTAL (BATCH*SEQ)   /* 4096 */
#define N_QKV   (3*D_MODEL)   /* 2304 */

typedef float  floatx4 __attribute__((ext_vector_type(4)));
typedef short  shortx8 __attribute__((ext_vector_type(8)));

#if __has_builtin(__builtin_amdgcn_exp2f)
#define EXP2(x) __builtin_amdgcn_exp2f(x)
#else
#define EXP2(x) exp2f(x)
#endif

/* scale folded into Q: (1/sqrt(64)) * log2(e) so softmax runs in exp2 domain */
#define Q_SCALE 0.18033688011112042f

static __device__ __forceinline__ unsigned short f2bf(float f) {
  __hip_bfloat16 h = __float2bfloat16(f);
  return *reinterpret_cast<unsigned short*>(&h);
}

static __device__ __forceinline__ void gload_lds16(const void* g, void* l) {
  auto gp = reinterpret_cast<const uint32_t __attribute__((address_space(1)))*>(
      reinterpret_cast<uintptr_t>(g));
  auto lp = reinterpret_cast<uint32_t __attribute__((address_space(3)))*>(
      reinterpret_cast<uintptr_t>(l));
  __builtin_amdgcn_global_load_lds(gp, lp, 16, 0, 0);
}

/* ---------------- convert fp32 -> bf16 (x, W_qkv, W_o) ---------------- */
__global__ void convert_bf16_kernel(const float* __restrict__ x,
                                    const float* __restrict__ wqkv,
                                    const float* __restrict__ wo,
                                    unsigned short* __restrict__ xb,
                                    unsigned short* __restrict__ wqkvb,
                                    unsigned short* __restrict__ wob) {
  const int NX = M_TOTAL * D_MODEL / 4;   // 786432
  const int NW = N_QKV * D_MODEL / 4;     // 442368
  const int NO = D_MODEL * D_MODEL / 4;   // 147456
  const int total = NX + NW + NO;
  for (int i = blockIdx.x * blockDim.x + threadIdx.x; i < total;
       i += gridDim.x * blockDim.x) {
    const float4* src; unsigned short* dst; int j;
    if (i < NX)            { src = (const float4*)x;    dst = xb;    j = i; }
    else if (i < NX + NW)  { src = (const float4*)wqkv; dst = wqkvb; j = i - NX; }
    else                   { src = (const float4*)wo;   dst = wob;   j = i - NX - NW; }
    float4 v = src[j];
    ushort4 o;
    o.x = f2bf(v.x); o.y = f2bf(v.y); o.z = f2bf(v.z); o.w = f2bf(v.w);
    *(ushort4*)(dst + (size_t)j * 4) = o;
  }
}

/* ---------------- QKV projection GEMM: [4096,768] @ [2304,768]^T ----------------
   Writes Q (scaled by Q_SCALE), K as [b,h,s,64] bf16; V transposed as [b,h,64,s]. */
__launch_bounds__(256, 2)
__global__ void qkv_gemm_kernel(const unsigned short* __restrict__ Xb,
                                const unsigned short* __restrict__ Wb,
                                const float* __restrict__ bias,
                                unsigned short* __restrict__ Qb,
                                unsigned short* __restrict__ Kb,
                                unsigned short* __restrict__ Vt) {
  __shared__ unsigned short Asub[128 * 32];
  __shared__ unsigned short Bsub[128 * 32];
  const int tid  = threadIdx.x;
  const int wave = tid >> 6;
  const int lane = tid & 63;
  const int m0 = blockIdx.y * 128;
  const int n0 = blockIdx.x * 128;
  const int wm = (wave >> 1) * 64;
  const int wn = (wave & 1) * 64;
  const int srow = lane >> 2;          // 0..15 within chunk
  const int scol = (lane & 3) * 8;     // k element offset
  const int col  = lane & 15;
  const int grp  = lane >> 4;
  floatx4 acc[4][4] = {};
  for (int kt = 0; kt < D_MODEL; kt += 32) {
    #pragma unroll
    for (int i = 0; i < 2; ++i) {
      int c = wave * 2 + i;
      int row = c * 16 + srow;
      gload_lds16(Xb + (size_t)(m0 + row) * D_MODEL + kt + scol, &Asub[c * 512]);
      gload_lds16(Wb + (size_t)(n0 + row) * D_MODEL + kt + scol, &Bsub[c * 512]);
    }
    __syncthreads();
    shortx8 af[4], bf[4];
    #pragma unroll
    for (int t = 0; t < 4; ++t) {
      af[t] = *(const shortx8*)&Asub[(wm + t * 16 + col) * 32 + grp * 8];
      bf[t] = *(const shortx8*)&Bsub[(wn + t * 16 + col) * 32 + grp * 8];
    }
    #pragma unroll
    for (int i = 0; i < 4; ++i)
      #pragma unroll
      for (int j = 0; j < 4; ++j)
        acc[i][j] = __builtin_amdgcn_mfma_f32_16x16x32_bf16(af[i], bf[j], acc[i][j], 0, 0, 0);
    __syncthreads();
  }
  /* epilogue: route to Q / K / Vt */
  #pragma unroll
  for (int i = 0; i < 4; ++i) {
    int mbase = m0 + wm + i * 16 + grp * 4;
    int b = mbase >> 11;
    int s = mbase & 2047;
    #pragma unroll
    for (int j = 0; j < 4; ++j) {
      int n   = n0 + wn + j * 16 + col;
      int sel = n / D_MODEL;
      int c   = n % D_MODEL;
      int h   = c >> 6, d = c & 63;
      int bh  = b * N_HEADS + h;
      float bv = bias[n];
      if (sel == 0) {
        #pragma unroll
        for (int r = 0; r < 4; ++r)
          Qb[((size_t)bh * SEQ + s + r) * D_HEAD + d] = f2bf((acc[i][j][r] + bv) * Q_SCALE);
      } else if (sel == 1) {
        #pragma unroll
        for (int r = 0; r < 4; ++r)
          Kb[((size_t)bh * SEQ + s + r) * D_HEAD + d] = f2bf(acc[i][j][r] + bv);
      } else {
        ushort4 o;
        o.x = f2bf(acc[i][j][0] + bv);
        o.y = f2bf(acc[i][j][1] + bv);
        o.z = f2bf(acc[i][j][2] + bv);
        o.w = f2bf(acc[i][j][3] + bv);
        *(ushort4*)&Vt[((size_t)bh * D_HEAD + d) * SEQ + s] = o;
      }
    }
  }
}

/* ---------------- causal flash attention ----------------
   1 wave per block, 16 q-rows per block. 3072 blocks, XCD-chunked (3 heads/XCD)
   and longest-first within chunk. Swapped QK^T (mfma(K,Q)) so each lane holds a
   full P column for one q row: softmax reduce = 2 shfl_xor; P packs to LDS as
   ds_write_b64 (consecutive kv). exp2 domain (scale pre-folded into Q). */
__launch_bounds__(64, 5)
__global__ void attn_kernel(const unsigned short* __restrict__ Qb,
                            const unsigned short* __restrict__ Kb,
                            const unsigned short* __restrict__ Vt,
                            unsigned short* __restrict__ Zb) {
  __shared__ unsigned short pw[16 * 64];   // P tile, XOR-swizzled at 16B granularity
  const int lane = threadIdx.x;
  const int col = lane & 15;
  const int grp = lane >> 4;

  /* block -> (bh, j): XCD c = i&7 owns v in [c*384, c*384+384) = 3 heads;
     within a head, j descends (longest blocks dispatch first). */
  const int i  = blockIdx.x;
  const int v  = (i & 7) * 384 + (i >> 3);
  const int bh = v >> 7;
  const int j  = 127 - (v & 127);
  const int q0 = j * 16;
  const int ktiles = ((q0 + 15) >> 6) + 1;

  const unsigned short* Qrow = Qb + ((size_t)bh * SEQ + q0 + col) * D_HEAD;
  shortx8 qf0 = *(const shortx8*)(Qrow + grp * 8);
  shortx8 qf1 = *(const shortx8*)(Qrow + 32 + grp * 8);

  floatx4 acc[4] = {};
  float mrun = -1e30f, lrun = 0.f;   // per-lane, q = q0 + col

  for (int kt = 0; kt < ktiles; ++kt) {
    const int kv0 = kt * 64;
    /* S^T = K Q^T : lane holds S[kv = kv0+nt*16+grp*4+r][q = q0+col] */
    floatx4 st[4];
    #pragma unroll
    for (int nt = 0; nt < 4; ++nt) {
      const unsigned short* Krow = Kb + ((size_t)bh * SEQ + kv0 + nt * 16 + col) * D_HEAD;
      shortx8 kf0 = *(const shortx8*)(Krow + grp * 8);
      shortx8 kf1 = *(const shortx8*)(Krow + 32 + grp * 8);
      floatx4 s = {};
      s = __builtin_amdgcn_mfma_f32_16x16x32_bf16(kf0, qf0, s, 0, 0, 0);
      s = __builtin_amdgcn_mfma_f32_16x16x32_bf16(kf1, qf1, s, 0, 0, 0);
      st[nt] = s;
    }
    /* causal mask: only the last tile can clip */
    float tmax = -1e30f;
    if (kt == ktiles - 1) {
      const int q = q0 + col;
      #pragma unroll
      for (int nt = 0; nt < 4; ++nt)
        #pragma unroll
        for (int r = 0; r < 4; ++r) {
          int kv = kv0 + nt * 16 + grp * 4 + r;
          float sv = (kv <= q) ? st[nt][r] : -1e30f;
          st[nt][r] = sv;
          tmax = fmaxf(tmax, sv);
        }
    } else {
      #pragma unroll
      for (int nt = 0; nt < 4; ++nt)
        #pragma unroll
        for (int r = 0; r < 4; ++r) tmax = fmaxf(tmax, st[nt][r]);
    }
    tmax = fmaxf(tmax, __shfl_xor(tmax, 16));
    tmax = fmaxf(tmax, __shfl_xor(tmax, 32));
    const float mnew  = fmaxf(mrun, tmax);
    const float alpha = EXP2(mrun - mnew);
    mrun = mnew;
    float rs = 0.f;
    #pragma unroll
    for (int nt = 0; nt < 4; ++nt)
      #pragma unroll
      for (int r = 0; r < 4; ++r) {
        float p = EXP2(st[nt][r] - mnew);
        st[nt][r] = p;
        rs += p;
      }
    rs += __shfl_xor(rs, 16);
    rs += __shfl_xor(rs, 32);
    lrun = lrun * alpha + rs;
    /* rescale accumulator: alpha lives in col-space, acc rows are grp*4+r */
    #pragma unroll
    for (int r = 0; r < 4; ++r) {
      float ar = __shfl(alpha, grp * 4 + r);
      #pragma unroll
      for (int dn = 0; dn < 4; ++dn) acc[dn][r] *= ar;
    }
    /* P -> LDS: lane's 4 r-values are consecutive kv for q=col -> one b64 write
       per nt. 16B-block XOR swizzle keeps writes/reads bank-balanced. */
    #pragma unroll
    for (int nt = 0; nt < 4; ++nt) {
      ushort4 po;
      po.x = f2bf(st[nt][0]); po.y = f2bf(st[nt][1]);
      po.z = f2bf(st[nt][2]); po.w = f2bf(st[nt][3]);
      int blk = (2 * nt + (grp >> 1)) ^ (col & 7);
      *(ushort4*)&pw[col * 64 + blk * 8 + 4 * (grp & 1)] = po;
    }
    /* Z += P V : A-frag = P[q=col][kv=32m+8grp..+7] via swizzled b128 read */
    #pragma unroll
    for (int m = 0; m < 2; ++m) {
      int blk = (4 * m + grp) ^ (col & 7);
      shortx8 pf = *(const shortx8*)&pw[col * 64 + blk * 8];
      #pragma unroll
      for (int dn = 0; dn < 4; ++dn) {
        const unsigned short* Vrow =
            Vt + ((size_t)bh * D_HEAD + dn * 16 + col) * SEQ + kv0 + m * 32 + grp * 8;
        shortx8 vf = *(const shortx8*)Vrow;
        acc[dn] = __builtin_amdgcn_mfma_f32_16x16x32_bf16(pf, vf, acc[dn], 0, 0, 0);
      }
    }
  }
  /* normalize (lrun is col-space; acc rows are grp*4+r) and write Z */
  const int b = bh / N_HEADS, h = bh % N_HEADS;
  #pragma unroll
  for (int r = 0; r < 4; ++r) {
    float lr = __shfl(lrun, grp * 4 + r);
    float li = 1.0f / lr;
    int q = q0 + grp * 4 + r;
    #pragma unroll
    for (int dn = 0; dn < 4; ++dn)
      Zb[((size_t)b * SEQ + q) * D_MODEL + h * 64 + dn * 16 + col] = f2bf(acc[dn][r] * li);
  }
}

/* ---------------- output projection: [4096,768] @ [768,768]^T + b_o -> fp32 ---- */
__launch_bounds__(256, 2)
__global__ void out_gemm_kernel(const unsigned short* __restrict__ Zb,
                                const unsigned short* __restrict__ Wob,
                                const float* __restrict__ bo,
                                float* __restrict__ Out) {
  __shared__ unsigned short Asub[128 * 32];
  __shared__ unsigned short Bsub[128 * 32];
  const int tid  = threadIdx.x;
  const int wave = tid >> 6;
  const int lane = tid & 63;
  const int m0 = blockIdx.y * 128;
  const int n0 = blockIdx.x * 128;
  const int wm = (wave >> 1) * 64;
  const int wn = (wave & 1) * 64;
  const int srow = lane >> 2;
  const int scol = (lane & 3) * 8;
  const int col  = lane & 15;
  const int grp  = lane >> 4;
  floatx4 acc[4][4] = {};
  for (int kt = 0; kt < D_MODEL; kt += 32) {
    #pragma unroll
    for (int i = 0; i < 2; ++i) {
      int c = wave * 2 + i;
      int row = c * 16 + srow;
      gload_lds16(Zb  + (size_t)(m0 + row) * D_MODEL + kt + scol, &Asub[c * 512]);
      gload_lds16(Wob + (size_t)(n0 + row) * D_MODEL + kt + scol, &Bsub[c * 512]);
    }
    __syncthreads();
    shortx8 af[4], bf[4];
    #pragma unroll
    for (int t = 0; t < 4; ++t) {
      af[t] = *(const shortx8*)&Asub[(wm + t * 16 + col) * 32 + grp * 8];
      bf[t] = *(const shortx8*)&Bsub[(wn + t * 16 + col) * 32 + grp * 8];
    }
    #pragma unroll
    for (int i = 0; i < 4; ++i)
      #pragma unroll
      for (int j = 0; j < 4; ++j)
        acc[i][j] = __builtin_amdgcn_mfma_f32_16x16x32_bf16(af[i], bf[j], acc[i][j], 0, 0, 0);
    __syncthreads();
  }
  #pragma unroll
  for (int i = 0; i < 4; ++i) {
    int mbase = m0 + wm + i * 16 + grp * 4;
    #pragma unroll
    for (int j = 0; j < 4; ++j) {
      int n = n0 + wn + j * 16 + col;
      float bv = bo[n];
      #pragma unroll
      for (int r = 0; r < 4; ++r)
        Out[(size_t)(mbase + r) * D_MODEL + n] = acc[i][j][r] + bv;
    }
  }
}

/* ---------------- launcher ---------------- */
extern "C" void kernel_launch(void* const* d_in, const int* in_sizes, int n_in,
                              void* d_out, int out_size, void* d_ws, size_t ws_size,
                              hipStream_t stream) {
  const float* x    = (const float*)d_in[0];
  const float* Wqkv = (const float*)d_in[1];
  const float* bqkv = (const float*)d_in[2];
  const float* Wo   = (const float*)d_in[3];
  const float* bo   = (const float*)d_in[4];
  float* out = (float*)d_out;

  unsigned short* ws = (unsigned short*)d_ws;
  const size_t SZ_X   = (size_t)M_TOTAL * D_MODEL;   // 3,145,728
  const size_t SZ_WQ  = (size_t)N_QKV * D_MODEL;     // 1,769,472
  const size_t SZ_WO  = (size_t)D_MODEL * D_MODEL;   //   589,824
  unsigned short* Xb    = ws;
  unsigned short* Wqkvb = Xb + SZ_X;
  unsigned short* Wob   = Wqkvb + SZ_WQ;
  unsigned short* Qb    = Wob + SZ_WO;
  unsigned short* Kb    = Qb + SZ_X;
  unsigned short* Vt    = Kb + SZ_X;
  unsigned short* Zb    = Vt + SZ_X;

  convert_bf16_kernel<<<dim3(1024), dim3(256), 0, stream>>>(x, Wqkv, Wo, Xb, Wqkvb, Wob);
  qkv_gemm_kernel<<<dim3(N_QKV / 128, M_TOTAL / 128), dim3(256), 0, stream>>>(
      Xb, Wqkvb, bqkv, Qb, Kb, Vt);
  attn_kernel<<<dim3(128 * BATCH * N_HEADS), dim3(64), 0, stream>>>(Qb, Kb, Vt, Zb);
  out_gemm_kernel<<<dim3(D_MODEL / 128, M_TOTAL / 128), dim3(256), 0, stream>>>(
      Zb, Wob, bo, out);
}